// Round 8
// baseline (147.165 us; speedup 1.0000x reference)
//
#include <hip/hip_runtime.h>

// B=32, F=node=128, T=2048, HID=256, NC=64, A=15 windows
// k_chain: 256 threads (4 waves), each wave owns 32 m-rows; launch_bounds(256,2)
// -> 256 VGPR cap (no spill), 2 blocks/CU (LDS-bound). Structure/barriers = R7.

typedef float f32x4 __attribute__((ext_vector_type(4)));
typedef __bf16 bf16x8 __attribute__((ext_vector_type(8)));
typedef unsigned short u16x8 __attribute__((ext_vector_type(8)));

__device__ inline unsigned short f2b(float f) {
  unsigned int u = __float_as_uint(f);
  unsigned int r = u + 0x7fffu + ((u >> 16) & 1u);
  return (unsigned short)(r >> 16);
}
__device__ inline float leaky(float v) { return v >= 0.f ? v : 0.2f * v; }

#define SWZ(k, r) ((k) ^ (((r) & 7) << 3))

// ---------------- k_prepw: W1/W2/W3 -> bf16 transposed ----------------
__global__ __launch_bounds__(256) void k_prepw(const float* __restrict__ W1,
                                               const float* __restrict__ W2,
                                               const float* __restrict__ W3,
                                               unsigned short* __restrict__ W1T,
                                               unsigned short* __restrict__ W2T,
                                               unsigned short* __restrict__ W3T) {
  __shared__ float t[64][65];
  const int bid = blockIdx.x;
  const int tid = threadIdx.x;
  const float* src;
  unsigned short* dst;
  int K, N, k0, n0;
  if (bid < 128) {        // W1 [2048][256] -> W1T [256][2048]
    src = W1; dst = W1T; K = 2048; N = 256;
    k0 = (bid >> 2) * 64; n0 = (bid & 3) * 64;
  } else if (bid < 144) { // W2 [256][256] -> W2T [256][256]
    src = W2; dst = W2T; K = 256; N = 256;
    int i = bid - 128; k0 = (i >> 2) * 64; n0 = (i & 3) * 64;
  } else {                // W3 [256][64] -> W3T [64][256]
    src = W3; dst = W3T; K = 256; N = 64;
    int i = bid - 144; k0 = i * 64; n0 = 0;
  }
#pragma unroll
  for (int it = 0; it < 16; ++it) {
    int e = tid + it * 256, r = e >> 6, c = e & 63;
    t[r][c] = src[(size_t)(k0 + r) * N + n0 + c];
  }
  __syncthreads();
#pragma unroll
  for (int it = 0; it < 16; ++it) {
    int e = tid + it * 256, rr = e >> 6, cc = e & 63;
    dst[(size_t)(n0 + rr) * K + k0 + cc] = f2b(t[cc][rr]);
  }
}

// ---------------- k_front: XW1T GEMM (bid<64) + xT transpose (bid>=64) ----
__global__ __launch_bounds__(512) void k_front(const float* __restrict__ x,
                                               const unsigned short* __restrict__ W1T,
                                               unsigned short* __restrict__ xT,
                                               unsigned short* __restrict__ XW1T) {
  __shared__ __align__(16) char ldsbuf[16896];
  const int bid = blockIdx.x;
  const int tid = threadIdx.x;
  if (bid >= 64) {
    // x [b][128 f][2048 t] fp32 -> xT [b][2048 t][128 f] bf16, 64x64 tiles
    float (*t)[65] = reinterpret_cast<float (*)[65]>(ldsbuf);
    int i = bid - 64;
    int b = i >> 6, rem = i & 63;
    int t0 = (rem >> 1) * 64, f0 = (rem & 1) * 64;
    const float* xb = x + ((size_t)b * 128 + f0) * 2048 + t0;
    int r = tid >> 3, c8 = (tid & 7) * 8;
    f32x4 v0 = *(const f32x4*)&xb[(size_t)r * 2048 + c8];
    f32x4 v1 = *(const f32x4*)&xb[(size_t)r * 2048 + c8 + 4];
    *(f32x4*)&t[r][c8] = v0;
    *(f32x4*)&t[r][c8 + 4] = v1;
    __syncthreads();
    u16x8 s;
#pragma unroll
    for (int q = 0; q < 8; ++q) s[q] = f2b(t[c8 + q][r]);
    *(u16x8*)&xT[((size_t)b * 2048 + t0 + r) * 128 + f0 + c8] = s;
  } else {
    // XW1T[b][hid 256][f0+0:64] = (x_b @ W1)^T ; A=W1T (L2), B=x tile (LDS dbuf)
    unsigned short (*sX)[64 * 64] = reinterpret_cast<unsigned short (*)[64 * 64]>(ldsbuf);
    const int b = bid >> 1, f0 = (bid & 1) * 64;
    const int w = tid >> 6, lane = tid & 63;
    const int l15 = lane & 15, l4 = lane >> 4;
    const float* xb = x + ((size_t)b * 128 + f0) * 2048;
    const int fr = tid >> 3, k8 = (tid & 7) * 8;
    f32x4 xr0, xr1;
    f32x4 acc[2][4] = {};

    auto LOADX = [&](int kb) {
      xr0 = *(const f32x4*)&xb[(size_t)fr * 2048 + kb * 64 + k8];
      xr1 = *(const f32x4*)&xb[(size_t)fr * 2048 + kb * 64 + k8 + 4];
    };
    auto STOREX = [&](int buf) {
      u16x8 s;
#pragma unroll
      for (int q = 0; q < 8; ++q) s[q] = f2b(q < 4 ? xr0[q] : xr1[q - 4]);
      *(u16x8*)&sX[buf][fr * 64 + SWZ(k8, fr)] = s;
    };

    LOADX(0);
    STOREX(0);
    __syncthreads();
    for (int kb = 0; kb < 32; ++kb) {
      if (kb < 31) LOADX(kb + 1);
      const int buf = kb & 1;
#pragma unroll
      for (int ks = 0; ks < 2; ++ks) {
        bf16x8 af[2];
#pragma unroll
        for (int mt = 0; mt < 2; ++mt)
          af[mt] = *(const bf16x8*)&W1T[(size_t)(w * 32 + mt * 16 + l15) * 2048 + kb * 64 + ks * 32 + l4 * 8];
#pragma unroll
        for (int nt = 0; nt < 4; ++nt) {
          int br = nt * 16 + l15;
          bf16x8 bf = *(const bf16x8*)&sX[buf][br * 64 + SWZ(ks * 32 + l4 * 8, br)];
#pragma unroll
          for (int mt = 0; mt < 2; ++mt)
            acc[mt][nt] = __builtin_amdgcn_mfma_f32_16x16x32_bf16(af[mt], bf, acc[mt][nt], 0, 0, 0);
        }
      }
      if (kb < 31) {
        STOREX(buf ^ 1);
        __syncthreads();
      }
    }
#pragma unroll
    for (int mt = 0; mt < 2; ++mt)
#pragma unroll
      for (int nt = 0; nt < 4; ++nt)
#pragma unroll
        for (int r = 0; r < 4; ++r) {
          int p = w * 32 + mt * 16 + l4 * 4 + r;
          XW1T[((size_t)b * 256 + p) * 128 + f0 + nt * 16 + l15] = f2b(acc[mt][nt][r]);
        }
  }
}

// ---------------- k_chain: 4 waves, 32 m-rows/wave, 256 VGPR budget ----------------
__global__ __launch_bounds__(256, 2) void k_chain(
    const unsigned short* __restrict__ xT, const unsigned short* __restrict__ XW1T,
    const unsigned short* __restrict__ W2T, const unsigned short* __restrict__ W3T,
    const float* __restrict__ b1g, const float* __restrict__ b2g,
    const float* __restrict__ b3g, float* __restrict__ gXa) {
  __shared__ __align__(16) unsigned short R0[128 * 128];  // adj -> h1b -> u2Ta/h2a -> u3T
  __shared__ __align__(16) unsigned short R1[128 * 128];  // win -> h1a -> u2Tb/h2b -> partials
  __shared__ float fS[256];  // [0:128) colsum, [128:256) diag

  const int tid = threadIdx.x;
  const int w = tid >> 6, lane = tid & 63;
  const int l15 = lane & 15, l4 = lane >> 4;
  // XCD-aware remap: 480 = 8 xcd * 60; same-b blocks land on one XCD
  const int ridx = (blockIdx.x & 7) * 60 + (blockIdx.x >> 3);
  const int b = ridx / 15, a = ridx % 15;
  const int m0 = w * 32;  // this wave owns rows m0..m0+31 (2 m-tiles)
  const unsigned short* XWb = XW1T + (size_t)b * 256 * 128;

  // ---- P0: win[node j][f] <- xT (coalesced bf16) into R1 ----
  const unsigned short* src = xT + ((size_t)b * 2048 + (size_t)a * 128) * 128;
#pragma unroll
  for (int it = 0; it < 8; ++it) {
    int tt = tid + it * 256;
    int j = tt >> 4, f8 = (tt & 15) * 8;
    *(u16x8*)&R1[j * 128 + SWZ(f8, j)] = *(const u16x8*)&src[j * 128 + f8];
  }
  __syncthreads();  // B0

  // ---- syrk + sums (MFMA ones); center+scale -> adj in R0 -> afj regs ----
  bf16x8 afj[2][4];
  {
    f32x4 acc8[2][8] = {};
    f32x4 sacc[2] = {};
    bf16x8 ones;
#pragma unroll
    for (int q = 0; q < 8; ++q) ones[q] = (__bf16)1.0f;
    __builtin_amdgcn_s_setprio(1);
#pragma unroll
    for (int ks = 0; ks < 4; ++ks) {
      bf16x8 af[2];
#pragma unroll
      for (int mt = 0; mt < 2; ++mt) {
        int ar = m0 + mt * 16 + l15;
        af[mt] = *(const bf16x8*)&R1[ar * 128 + SWZ(ks * 32 + l4 * 8, ar)];
        sacc[mt] = __builtin_amdgcn_mfma_f32_16x16x32_bf16(af[mt], ones, sacc[mt], 0, 0, 0);
      }
#pragma unroll
      for (int nt = 0; nt < 8; ++nt) {
        int br = nt * 16 + l15;
        bf16x8 bf = *(const bf16x8*)&R1[br * 128 + SWZ(ks * 32 + l4 * 8, br)];
#pragma unroll
        for (int mt = 0; mt < 2; ++mt)
          acc8[mt][nt] = __builtin_amdgcn_mfma_f32_16x16x32_bf16(af[mt], bf, acc8[mt][nt], 0, 0, 0);
      }
    }
    __builtin_amdgcn_s_setprio(0);
    if (l15 == 0) {
#pragma unroll
      for (int mt = 0; mt < 2; ++mt)
#pragma unroll
        for (int r = 0; r < 4; ++r) fS[m0 + mt * 16 + l4 * 4 + r] = sacc[mt][r];
    }
    __syncthreads();  // B1: sums visible; all syrk reads of R1 done
    const float inv128 = 1.f / 128.f;
    float fcol[8];
#pragma unroll
    for (int nt = 0; nt < 8; ++nt) fcol[nt] = fS[nt * 16 + l15];
#pragma unroll
    for (int mt = 0; mt < 2; ++mt)
#pragma unroll
      for (int nt = 0; nt < 8; ++nt)
#pragma unroll
        for (int r = 0; r < 4; ++r) {
          int row = m0 + mt * 16 + l4 * 4 + r, col = nt * 16 + l15;
          float c = acc8[mt][nt][r] - sacc[mt][r] * fcol[nt] * inv128;
          acc8[mt][nt][r] = c;
          if (row == col) fS[128 + row] = c;
        }
    __syncthreads();  // B2: diag visible
    float djv[8], div[2][4];
#pragma unroll
    for (int nt = 0; nt < 8; ++nt) {
      float d = fS[128 + nt * 16 + l15];
      djv[nt] = d > 0.f ? __frsqrt_rn(d) : 0.f;
    }
#pragma unroll
    for (int mt = 0; mt < 2; ++mt)
#pragma unroll
      for (int r = 0; r < 4; ++r) {
        float d = fS[128 + m0 + mt * 16 + l4 * 4 + r];
        div[mt][r] = d > 0.f ? __frsqrt_rn(d) : 0.f;
      }
#pragma unroll
    for (int mt = 0; mt < 2; ++mt)
#pragma unroll
      for (int nt = 0; nt < 8; ++nt)
#pragma unroll
        for (int r = 0; r < 4; ++r) {
          int row = m0 + mt * 16 + l4 * 4 + r, col = nt * 16 + l15;
          float v = acc8[mt][nt][r] * div[mt][r] * djv[nt];
          v = fminf(1.f, fmaxf(-1.f, v));
          v = 0.5f * v + 0.5f;
          if (div[mt][r] == 0.f || djv[nt] == 0.f) v = 0.f;  // nan_to_num
          R0[row * 128 + SWZ(col, row)] = f2b(v);
        }
    // adj rows m0..m0+31 fully written by THIS wave (full n per wave) -> no barrier
#pragma unroll
    for (int mt = 0; mt < 2; ++mt)
#pragma unroll
      for (int ks = 0; ks < 4; ++ks) {
        int ar = m0 + mt * 16 + l15;
        afj[mt][ks] = *(const bf16x8*)&R0[ar * 128 + SWZ(ks * 32 + l4 * 8, ar)];
      }
  }
  // No barrier: op1 stores only touch this wave's own rows.

  // ---- op1: h1 = leaky(adj @ XW1b + b1); hid0:128 -> R1, hid128:256 -> R0 ----
#pragma unroll 1
  for (int half = 0; half < 2; ++half) {
    f32x4 acc[2][8] = {};
    __builtin_amdgcn_s_setprio(1);
#pragma unroll
    for (int ks = 0; ks < 4; ++ks)
#pragma unroll
      for (int nt = 0; nt < 8; ++nt) {
        bf16x8 bf = *(const bf16x8*)&XWb[(size_t)(half * 128 + nt * 16 + l15) * 128 + ks * 32 + l4 * 8];
#pragma unroll
        for (int mt = 0; mt < 2; ++mt)
          acc[mt][nt] = __builtin_amdgcn_mfma_f32_16x16x32_bf16(afj[mt][ks], bf, acc[mt][nt], 0, 0, 0);
      }
    __builtin_amdgcn_s_setprio(0);
    unsigned short* Rd = half ? R0 : R1;
#pragma unroll
    for (int mt = 0; mt < 2; ++mt)
#pragma unroll
      for (int nt = 0; nt < 8; ++nt) {
        float bias = b1g[half * 128 + nt * 16 + l15];
#pragma unroll
        for (int r = 0; r < 4; ++r) {
          int row = m0 + mt * 16 + l4 * 4 + r, col = nt * 16 + l15;
          Rd[row * 128 + SWZ(col, row)] = f2b(leaky(acc[mt][nt][r] + bias));
        }
      }
  }
  __syncthreads();  // B3: h1 complete (both halves)

  // ---- op2: u2T = W2T @ h1^T, full K=256 (k<128 from R1, k>=128 from R0) ----
  f32x4 u2[4][8] = {};
  {
    __builtin_amdgcn_s_setprio(1);
#pragma unroll
    for (int ks = 0; ks < 8; ++ks) {
      bf16x8 aw[4];
#pragma unroll
      for (int mi = 0; mi < 4; ++mi)
        aw[mi] = *(const bf16x8*)&W2T[(size_t)(w * 64 + mi * 16 + l15) * 256 + ks * 32 + l4 * 8];
      const unsigned short* Rs = (ks < 4) ? R1 : R0;
      int kk = (ks & 3) * 32 + l4 * 8;
#pragma unroll
      for (int nt = 0; nt < 8; ++nt) {
        int br = nt * 16 + l15;
        bf16x8 bf = *(const bf16x8*)&Rs[br * 128 + SWZ(kk, br)];
#pragma unroll
        for (int mi = 0; mi < 4; ++mi)
          u2[mi][nt] = __builtin_amdgcn_mfma_f32_16x16x32_bf16(aw[mi], bf, u2[mi][nt], 0, 0, 0);
      }
    }
    __builtin_amdgcn_s_setprio(0);
  }
  __syncthreads();  // B4: all h1 reads done

  // ---- store u2T [hid][node]: hid<128 -> R0, else R1 ----
#pragma unroll
  for (int mi = 0; mi < 4; ++mi)
#pragma unroll
    for (int nt = 0; nt < 8; ++nt)
#pragma unroll
      for (int r = 0; r < 4; ++r) {
        int grow = w * 64 + mi * 16 + l4 * 4 + r;
        int col = nt * 16 + l15;
        unsigned short* Rd = (grow < 128) ? R0 : R1;
        int lr = grow & 127;
        Rd[lr * 128 + SWZ(col, lr)] = f2b(u2[mi][nt][r]);
      }
  __syncthreads();  // B5: u2T stored

  // ---- op3: h2 = leaky(adj @ u2 + b2), full hid 256 ----
  f32x4 h2acc[2][16];
#pragma unroll
  for (int mt = 0; mt < 2; ++mt)
#pragma unroll
    for (int nt = 0; nt < 16; ++nt) h2acc[mt][nt] = f32x4{0.f, 0.f, 0.f, 0.f};
  __builtin_amdgcn_s_setprio(1);
#pragma unroll
  for (int ks = 0; ks < 4; ++ks)
#pragma unroll
    for (int nt = 0; nt < 16; ++nt) {
      int brl = (nt & 7) * 16 + l15;
      const unsigned short* Rs = (nt < 8) ? R0 : R1;
      bf16x8 bf = *(const bf16x8*)&Rs[brl * 128 + SWZ(ks * 32 + l4 * 8, brl)];
#pragma unroll
      for (int mt = 0; mt < 2; ++mt)
        h2acc[mt][nt] = __builtin_amdgcn_mfma_f32_16x16x32_bf16(afj[mt][ks], bf, h2acc[mt][nt], 0, 0, 0);
    }
  __builtin_amdgcn_s_setprio(0);
  __syncthreads();  // B6: all u2T reads done

  // ---- store h2 [node][hid]: hid<128 cols -> R0, else R1 ----
#pragma unroll
  for (int mt = 0; mt < 2; ++mt)
#pragma unroll
    for (int nt = 0; nt < 16; ++nt) {
      float bias = b2g[nt * 16 + l15];
#pragma unroll
      for (int r = 0; r < 4; ++r) {
        int row = m0 + mt * 16 + l4 * 4 + r;
        int coll = (nt & 7) * 16 + l15;
        unsigned short* Rd = (nt < 8) ? R0 : R1;
        Rd[row * 128 + SWZ(coll, row)] = f2b(leaky(h2acc[mt][nt][r] + bias));
      }
    }
  __syncthreads();  // B7: h2 stored

  // ---- op4: u3T = W3T @ h2^T, full K=256 (R0 then R1) ----
  f32x4 u3[8] = {};
  __builtin_amdgcn_s_setprio(1);
#pragma unroll
  for (int ks = 0; ks < 8; ++ks) {
    bf16x8 a3 = *(const bf16x8*)&W3T[(size_t)(w * 16 + l15) * 256 + ks * 32 + l4 * 8];
    const unsigned short* Rs = (ks < 4) ? R0 : R1;
    int kk = (ks & 3) * 32 + l4 * 8;
#pragma unroll
    for (int nt = 0; nt < 8; ++nt) {
      int br = nt * 16 + l15;
      bf16x8 bf = *(const bf16x8*)&Rs[br * 128 + SWZ(kk, br)];
      u3[nt] = __builtin_amdgcn_mfma_f32_16x16x32_bf16(a3, bf, u3[nt], 0, 0, 0);
    }
  }
  __builtin_amdgcn_s_setprio(0);
  __syncthreads();  // B8: all h2 reads done

  // ---- store u3T [cls][node] -> R0 rows 0..63 ----
#pragma unroll
  for (int nt = 0; nt < 8; ++nt)
#pragma unroll
    for (int r = 0; r < 4; ++r) {
      int grow = w * 16 + l4 * 4 + r;          // 0..63 (class)
      int col = nt * 16 + l15;                 // 0..127 (node)
      R0[grow * 128 + SWZ(col, grow)] = f2b(u3[nt][r]);
    }
  __syncthreads();  // B9: u3T stored

  // ---- op5: xa = leaky(adj @ u3 + b3); mean over node via shuffles ----
  {
    f32x4 xacc[2][4] = {};
    __builtin_amdgcn_s_setprio(1);
#pragma unroll
    for (int ks = 0; ks < 4; ++ks)
#pragma unroll
      for (int nt = 0; nt < 4; ++nt) {
        int br = nt * 16 + l15;
        bf16x8 bf = *(const bf16x8*)&R0[br * 128 + SWZ(ks * 32 + l4 * 8, br)];
#pragma unroll
        for (int mt = 0; mt < 2; ++mt)
          xacc[mt][nt] = __builtin_amdgcn_mfma_f32_16x16x32_bf16(afj[mt][ks], bf, xacc[mt][nt], 0, 0, 0);
      }
    __builtin_amdgcn_s_setprio(0);
    float* pf = reinterpret_cast<float*>(R1);  // R1 dead after op4
#pragma unroll
    for (int mt = 0; mt < 2; ++mt)
#pragma unroll
      for (int nt = 0; nt < 4; ++nt) {
        float bias = b3g[nt * 16 + l15];
        float v = 0.f;
#pragma unroll
        for (int r = 0; r < 4; ++r) v += leaky(xacc[mt][nt][r] + bias);
        v += __shfl_xor(v, 16);
        v += __shfl_xor(v, 32);
        if (l4 == 0) pf[(w * 2 + mt) * 64 + nt * 16 + l15] = v;
      }
  }
  __syncthreads();  // B10: partials written
  if (tid < 64) {
    const float* pf = reinterpret_cast<const float*>(R1);
    float s = 0.f;
#pragma unroll
    for (int gg = 0; gg < 8; ++gg) s += pf[gg * 64 + tid];
    gXa[((size_t)b * 15 + a) * 64 + tid] = s * (1.f / 128.f);
  }
}

// ---------------- k_head: per-batch head ----------------
__global__ __launch_bounds__(256) void k_head(const float* __restrict__ gXa,
                                              const float* __restrict__ W4,
                                              const float* __restrict__ b4,
                                              float* __restrict__ out) {
  __shared__ float xb[15 * 64];
  __shared__ float c2[15 * 16];
  __shared__ float mu[15];
  __shared__ float dinv[15];
  __shared__ float yy[15 * 64];
  __shared__ float zz[15 * 64];
  const int b = blockIdx.x;
  const int tid = threadIdx.x;
  for (int e = tid; e < 960; e += 256) xb[e] = gXa[(size_t)b * 960 + e];
  __syncthreads();
  if (tid < 15) {
    float s = 0.f;
    for (int c = 0; c < 64; ++c) s += xb[tid * 64 + c];
    mu[tid] = s * (1.f / 64.f);
  }
  __syncthreads();
  if (tid < 225) {
    int p = tid / 15, q = tid % 15;
    float s = 0.f;
    for (int c = 0; c < 64; ++c)
      s += (xb[p * 64 + c] - mu[p]) * (xb[q * 64 + c] - mu[q]);
    c2[p * 16 + q] = s;
  }
  __syncthreads();
  if (tid < 15) {
    float d = c2[tid * 16 + tid];
    dinv[tid] = d > 0.f ? (1.f / sqrtf(d)) : 0.f;
  }
  __syncthreads();
  if (tid < 225) {
    int p = tid / 15, q = tid % 15;
    float v = c2[p * 16 + q] * dinv[p] * dinv[q];
    v = fminf(1.f, fmaxf(-1.f, v));
    if (dinv[p] == 0.f || dinv[q] == 0.f) v = 0.f;
    c2[p * 16 + q] = v;
  }
  __syncthreads();
  for (int e = tid; e < 960; e += 256) {
    int p = e >> 6, c = e & 63;
    float s = 0.f;
    for (int q = 0; q < 15; ++q) s += c2[p * 16 + q] * xb[q * 64 + c];
    yy[e] = s;
  }
  __syncthreads();
  for (int e = tid; e < 960; e += 256) {
    int p = e >> 6, c = e & 63;
    float s = b4[c];
    for (int k = 0; k < 64; ++k) s += yy[p * 64 + k] * W4[k * 64 + c];
    zz[e] = leaky(s);
  }
  __syncthreads();
  if (tid < 64) {
    float m = -INFINITY;
    for (int p = 0; p < 15; ++p) m = fmaxf(m, zz[p * 64 + tid]);
    out[(size_t)b * 64 + tid] = m;
  }
}

extern "C" void kernel_launch(void* const* d_in, const int* in_sizes, int n_in,
                              void* d_out, int out_size, void* d_ws, size_t ws_size,
                              hipStream_t stream) {
  const float* x  = (const float*)d_in[0];
  const float* W1 = (const float*)d_in[1];
  const float* b1 = (const float*)d_in[2];
  const float* W2 = (const float*)d_in[3];
  const float* b2 = (const float*)d_in[4];
  const float* W3 = (const float*)d_in[5];
  const float* b3 = (const float*)d_in[6];
  const float* W4 = (const float*)d_in[7];
  const float* b4 = (const float*)d_in[8];
  float* out = (float*)d_out;

  char* ws = (char*)d_ws;
  unsigned short* xT   = (unsigned short*)ws;                 // 32*2048*128*2 = 16 MB
  unsigned short* XW1T = (unsigned short*)(ws + 16777216);    // 2 MB
  unsigned short* W1T  = (unsigned short*)(ws + 18874368);    // 1 MB
  unsigned short* W2T  = (unsigned short*)(ws + 19922944);    // 128 KB
  unsigned short* W3T  = (unsigned short*)(ws + 20054016);    // 32 KB
  float* gXa           = (float*)(ws + 20086784);             // 120 KB

  k_prepw<<<148, 256, 0, stream>>>(W1, W2, W3, W1T, W2T, W3T);
  k_front<<<2112, 512, 0, stream>>>(x, W1T, xT, XW1T);
  k_chain<<<480, 256, 0, stream>>>(xT, XW1T, W2T, W3T, b1, b2, b3, gXa);
  k_head<<<32, 256, 0, stream>>>(gXa, W4, b4, out);
}

// Round 9
// 133.967 us; speedup vs baseline: 1.0985x; 1.0985x over previous
//
#include <hip/hip_runtime.h>

// B=32, F=node=128, T=2048, HID=256, NC=64, A=15 windows
// R7 structure; __launch_bounds__(512) WITHOUT min-waves clause (anti-spill).
// k_chain: 8 waves, 11 barriers, full-K phases, adj in regs, 66.5KB LDS.

typedef float f32x4 __attribute__((ext_vector_type(4)));
typedef __bf16 bf16x8 __attribute__((ext_vector_type(8)));
typedef unsigned short u16x8 __attribute__((ext_vector_type(8)));

__device__ inline unsigned short f2b(float f) {
  unsigned int u = __float_as_uint(f);
  unsigned int r = u + 0x7fffu + ((u >> 16) & 1u);
  return (unsigned short)(r >> 16);
}
__device__ inline float leaky(float v) { return v >= 0.f ? v : 0.2f * v; }

#define SWZ(k, r) ((k) ^ (((r) & 7) << 3))

// ---------------- k_prepw: W1/W2/W3 -> bf16 transposed ----------------
__global__ __launch_bounds__(256) void k_prepw(const float* __restrict__ W1,
                                               const float* __restrict__ W2,
                                               const float* __restrict__ W3,
                                               unsigned short* __restrict__ W1T,
                                               unsigned short* __restrict__ W2T,
                                               unsigned short* __restrict__ W3T) {
  __shared__ float t[64][65];
  const int bid = blockIdx.x;
  const int tid = threadIdx.x;
  const float* src;
  unsigned short* dst;
  int K, N, k0, n0;
  if (bid < 128) {        // W1 [2048][256] -> W1T [256][2048]
    src = W1; dst = W1T; K = 2048; N = 256;
    k0 = (bid >> 2) * 64; n0 = (bid & 3) * 64;
  } else if (bid < 144) { // W2 [256][256] -> W2T [256][256]
    src = W2; dst = W2T; K = 256; N = 256;
    int i = bid - 128; k0 = (i >> 2) * 64; n0 = (i & 3) * 64;
  } else {                // W3 [256][64] -> W3T [64][256]
    src = W3; dst = W3T; K = 256; N = 64;
    int i = bid - 144; k0 = i * 64; n0 = 0;
  }
#pragma unroll
  for (int it = 0; it < 16; ++it) {
    int e = tid + it * 256, r = e >> 6, c = e & 63;
    t[r][c] = src[(size_t)(k0 + r) * N + n0 + c];
  }
  __syncthreads();
#pragma unroll
  for (int it = 0; it < 16; ++it) {
    int e = tid + it * 256, rr = e >> 6, cc = e & 63;
    dst[(size_t)(n0 + rr) * K + k0 + cc] = f2b(t[cc][rr]);
  }
}

// ---------------- k_front: XW1T GEMM (bid<64) + xT transpose (bid>=64) ----
__global__ __launch_bounds__(512) void k_front(const float* __restrict__ x,
                                               const unsigned short* __restrict__ W1T,
                                               unsigned short* __restrict__ xT,
                                               unsigned short* __restrict__ XW1T) {
  __shared__ __align__(16) char ldsbuf[16896];
  const int bid = blockIdx.x;
  const int tid = threadIdx.x;
  if (bid >= 64) {
    // x [b][128 f][2048 t] fp32 -> xT [b][2048 t][128 f] bf16, 64x64 tiles
    float (*t)[65] = reinterpret_cast<float (*)[65]>(ldsbuf);
    int i = bid - 64;
    int b = i >> 6, rem = i & 63;
    int t0 = (rem >> 1) * 64, f0 = (rem & 1) * 64;
    const float* xb = x + ((size_t)b * 128 + f0) * 2048 + t0;
    int r = tid >> 3, c8 = (tid & 7) * 8;
    f32x4 v0 = *(const f32x4*)&xb[(size_t)r * 2048 + c8];
    f32x4 v1 = *(const f32x4*)&xb[(size_t)r * 2048 + c8 + 4];
    *(f32x4*)&t[r][c8] = v0;
    *(f32x4*)&t[r][c8 + 4] = v1;
    __syncthreads();
    u16x8 s;
#pragma unroll
    for (int q = 0; q < 8; ++q) s[q] = f2b(t[c8 + q][r]);
    *(u16x8*)&xT[((size_t)b * 2048 + t0 + r) * 128 + f0 + c8] = s;
  } else {
    // XW1T[b][hid 256][f0+0:64] = (x_b @ W1)^T ; A=W1T (L2), B=x tile (LDS dbuf)
    unsigned short (*sX)[64 * 64] = reinterpret_cast<unsigned short (*)[64 * 64]>(ldsbuf);
    const int b = bid >> 1, f0 = (bid & 1) * 64;
    const int w = tid >> 6, lane = tid & 63;
    const int l15 = lane & 15, l4 = lane >> 4;
    const float* xb = x + ((size_t)b * 128 + f0) * 2048;
    const int fr = tid >> 3, k8 = (tid & 7) * 8;
    f32x4 xr0, xr1;
    f32x4 acc[2][4] = {};

    auto LOADX = [&](int kb) {
      xr0 = *(const f32x4*)&xb[(size_t)fr * 2048 + kb * 64 + k8];
      xr1 = *(const f32x4*)&xb[(size_t)fr * 2048 + kb * 64 + k8 + 4];
    };
    auto STOREX = [&](int buf) {
      u16x8 s;
#pragma unroll
      for (int q = 0; q < 8; ++q) s[q] = f2b(q < 4 ? xr0[q] : xr1[q - 4]);
      *(u16x8*)&sX[buf][fr * 64 + SWZ(k8, fr)] = s;
    };

    LOADX(0);
    STOREX(0);
    __syncthreads();
    for (int kb = 0; kb < 32; ++kb) {
      if (kb < 31) LOADX(kb + 1);
      const int buf = kb & 1;
#pragma unroll
      for (int ks = 0; ks < 2; ++ks) {
        bf16x8 af[2];
#pragma unroll
        for (int mt = 0; mt < 2; ++mt)
          af[mt] = *(const bf16x8*)&W1T[(size_t)(w * 32 + mt * 16 + l15) * 2048 + kb * 64 + ks * 32 + l4 * 8];
#pragma unroll
        for (int nt = 0; nt < 4; ++nt) {
          int br = nt * 16 + l15;
          bf16x8 bf = *(const bf16x8*)&sX[buf][br * 64 + SWZ(ks * 32 + l4 * 8, br)];
#pragma unroll
          for (int mt = 0; mt < 2; ++mt)
            acc[mt][nt] = __builtin_amdgcn_mfma_f32_16x16x32_bf16(af[mt], bf, acc[mt][nt], 0, 0, 0);
        }
      }
      if (kb < 31) {
        STOREX(buf ^ 1);
        __syncthreads();
      }
    }
#pragma unroll
    for (int mt = 0; mt < 2; ++mt)
#pragma unroll
      for (int nt = 0; nt < 4; ++nt)
#pragma unroll
        for (int r = 0; r < 4; ++r) {
          int p = w * 32 + mt * 16 + l4 * 4 + r;
          XW1T[((size_t)b * 256 + p) * 128 + f0 + nt * 16 + l15] = f2b(acc[mt][nt][r]);
        }
  }
}

// ---------------- k_chain: per-(b,a) fused MFMA chain, 11 barriers ----------------
__global__ __launch_bounds__(512) void k_chain(
    const unsigned short* __restrict__ xT, const unsigned short* __restrict__ XW1T,
    const unsigned short* __restrict__ W2T, const unsigned short* __restrict__ W3T,
    const float* __restrict__ b1g, const float* __restrict__ b2g,
    const float* __restrict__ b3g, float* __restrict__ gXa) {
  __shared__ __align__(16) unsigned short R0[128 * 128];  // adj -> h1b -> u2Ta/h2a -> u3T
  __shared__ __align__(16) unsigned short R1[128 * 128];  // win -> h1a -> u2Tb/h2b -> partials
  __shared__ float fS[256];  // [0:128) colsum, [128:256) diag

  const int tid = threadIdx.x;
  const int w = tid >> 6, lane = tid & 63;
  const int l15 = lane & 15, l4 = lane >> 4;
  // XCD-aware remap: 480 = 8 xcd * 60; same-b blocks land on one XCD
  const int ridx = (blockIdx.x & 7) * 60 + (blockIdx.x >> 3);
  const int b = ridx / 15, a = ridx % 15;
  const int m0 = w * 16;
  const unsigned short* XWb = XW1T + (size_t)b * 256 * 128;

  // ---- P0: win[node j][f] <- xT (coalesced bf16) into R1 ----
  const unsigned short* src = xT + ((size_t)b * 2048 + (size_t)a * 128) * 128;
#pragma unroll
  for (int it = 0; it < 4; ++it) {
    int tt = tid + it * 512;
    int j = tt >> 4, f8 = (tt & 15) * 8;
    *(u16x8*)&R1[j * 128 + SWZ(f8, j)] = *(const u16x8*)&src[j * 128 + f8];
  }
  __syncthreads();  // B0

  // ---- syrk + sums (MFMA ones); center+scale -> adj in R0 -> afj regs ----
  bf16x8 afj[4];
  {
    f32x4 acc8[8] = {};
    f32x4 sacc = {};
    bf16x8 ones;
#pragma unroll
    for (int q = 0; q < 8; ++q) ones[q] = (__bf16)1.0f;
    __builtin_amdgcn_s_setprio(1);
#pragma unroll
    for (int ks = 0; ks < 4; ++ks) {
      int ar = m0 + l15;
      bf16x8 af = *(const bf16x8*)&R1[ar * 128 + SWZ(ks * 32 + l4 * 8, ar)];
      sacc = __builtin_amdgcn_mfma_f32_16x16x32_bf16(af, ones, sacc, 0, 0, 0);
#pragma unroll
      for (int nt = 0; nt < 8; ++nt) {
        int br = nt * 16 + l15;
        bf16x8 bf = *(const bf16x8*)&R1[br * 128 + SWZ(ks * 32 + l4 * 8, br)];
        acc8[nt] = __builtin_amdgcn_mfma_f32_16x16x32_bf16(af, bf, acc8[nt], 0, 0, 0);
      }
    }
    __builtin_amdgcn_s_setprio(0);
    if (l15 == 0) {
#pragma unroll
      for (int r = 0; r < 4; ++r) fS[m0 + l4 * 4 + r] = sacc[r];
    }
    __syncthreads();  // B1: sums visible; all syrk reads of R1 done
    const float inv128 = 1.f / 128.f;
    float fcol[8];
#pragma unroll
    for (int nt = 0; nt < 8; ++nt) fcol[nt] = fS[nt * 16 + l15];
#pragma unroll
    for (int nt = 0; nt < 8; ++nt)
#pragma unroll
      for (int r = 0; r < 4; ++r) {
        int row = m0 + l4 * 4 + r, col = nt * 16 + l15;
        float c = acc8[nt][r] - sacc[r] * fcol[nt] * inv128;
        acc8[nt][r] = c;
        if (row == col) fS[128 + row] = c;
      }
    __syncthreads();  // B2: diag visible
    // per-lane redundant rsqrt (no serialized section)
    float djv[8], div[4];
#pragma unroll
    for (int nt = 0; nt < 8; ++nt) {
      float d = fS[128 + nt * 16 + l15];
      djv[nt] = d > 0.f ? __frsqrt_rn(d) : 0.f;
    }
#pragma unroll
    for (int r = 0; r < 4; ++r) {
      float d = fS[128 + m0 + l4 * 4 + r];
      div[r] = d > 0.f ? __frsqrt_rn(d) : 0.f;
    }
#pragma unroll
    for (int nt = 0; nt < 8; ++nt)
#pragma unroll
      for (int r = 0; r < 4; ++r) {
        int row = m0 + l4 * 4 + r, col = nt * 16 + l15;
        float v = acc8[nt][r] * div[r] * djv[nt];
        v = fminf(1.f, fmaxf(-1.f, v));
        v = 0.5f * v + 0.5f;
        if (div[r] == 0.f || djv[nt] == 0.f) v = 0.f;  // nan_to_num
        R0[row * 128 + SWZ(col, row)] = f2b(v);
      }
    // adj rows m0..m0+15: same-wave write->read (LDS in-order per wave)
#pragma unroll
    for (int ks = 0; ks < 4; ++ks)
      afj[ks] = *(const bf16x8*)&R0[(m0 + l15) * 128 + SWZ(ks * 32 + l4 * 8, m0 + l15)];
  }
  // No barrier: from here to B3, each wave touches only its OWN rows of R0/R1.

  // ---- op1: h1 = leaky(adj @ XW1b + b1); hid0:128 -> R1, hid128:256 -> R0 ----
#pragma unroll 1
  for (int half = 0; half < 2; ++half) {
    f32x4 acc[8] = {};
    __builtin_amdgcn_s_setprio(1);
#pragma unroll
    for (int ks = 0; ks < 4; ++ks)
#pragma unroll
      for (int nt = 0; nt < 8; ++nt) {
        bf16x8 bf = *(const bf16x8*)&XWb[(size_t)(half * 128 + nt * 16 + l15) * 128 + ks * 32 + l4 * 8];
        acc[nt] = __builtin_amdgcn_mfma_f32_16x16x32_bf16(afj[ks], bf, acc[nt], 0, 0, 0);
      }
    __builtin_amdgcn_s_setprio(0);
    unsigned short* Rd = half ? R0 : R1;
#pragma unroll
    for (int nt = 0; nt < 8; ++nt) {
      float bias = b1g[half * 128 + nt * 16 + l15];
#pragma unroll
      for (int r = 0; r < 4; ++r) {
        int row = m0 + l4 * 4 + r, col = nt * 16 + l15;
        Rd[row * 128 + SWZ(col, row)] = f2b(leaky(acc[nt][r] + bias));
      }
    }
  }
  __syncthreads();  // B3: h1 complete (both halves)

  // ---- op2: u2T = W2T @ h1^T, full K=256 (k<128 from R1, k>=128 from R0) ----
  f32x4 u2[2][8] = {};
  {
    __builtin_amdgcn_s_setprio(1);
#pragma unroll
    for (int ks = 0; ks < 8; ++ks) {
      bf16x8 a0 = *(const bf16x8*)&W2T[(size_t)(w * 32 + l15) * 256 + ks * 32 + l4 * 8];
      bf16x8 a1 = *(const bf16x8*)&W2T[(size_t)(w * 32 + 16 + l15) * 256 + ks * 32 + l4 * 8];
      const unsigned short* Rs = (ks < 4) ? R1 : R0;
      int kk = (ks & 3) * 32 + l4 * 8;
#pragma unroll
      for (int nt = 0; nt < 8; ++nt) {
        int br = nt * 16 + l15;
        bf16x8 bf = *(const bf16x8*)&Rs[br * 128 + SWZ(kk, br)];
        u2[0][nt] = __builtin_amdgcn_mfma_f32_16x16x32_bf16(a0, bf, u2[0][nt], 0, 0, 0);
        u2[1][nt] = __builtin_amdgcn_mfma_f32_16x16x32_bf16(a1, bf, u2[1][nt], 0, 0, 0);
      }
    }
    __builtin_amdgcn_s_setprio(0);
  }
  __syncthreads();  // B4: all h1 reads done

  // ---- store u2T [hid][node]: hid<128 -> R0, else R1 ----
#pragma unroll
  for (int mt = 0; mt < 2; ++mt)
#pragma unroll
    for (int nt = 0; nt < 8; ++nt)
#pragma unroll
      for (int r = 0; r < 4; ++r) {
        int grow = w * 32 + mt * 16 + l4 * 4 + r;
        int col = nt * 16 + l15;
        unsigned short* Rd = (grow < 128) ? R0 : R1;
        int lr = grow & 127;
        Rd[lr * 128 + SWZ(col, lr)] = f2b(u2[mt][nt][r]);
      }
  __syncthreads();  // B5: u2T stored

  // ---- op3: h2 = leaky(adj @ u2 + b2), full hid 256 ----
  f32x4 h2acc[16];
#pragma unroll
  for (int nt = 0; nt < 16; ++nt) h2acc[nt] = f32x4{0.f, 0.f, 0.f, 0.f};
  __builtin_amdgcn_s_setprio(1);
#pragma unroll
  for (int ks = 0; ks < 4; ++ks)
#pragma unroll
    for (int nt = 0; nt < 16; ++nt) {
      int brl = (nt & 7) * 16 + l15;
      const unsigned short* Rs = (nt < 8) ? R0 : R1;
      bf16x8 bf = *(const bf16x8*)&Rs[brl * 128 + SWZ(ks * 32 + l4 * 8, brl)];
      h2acc[nt] = __builtin_amdgcn_mfma_f32_16x16x32_bf16(afj[ks], bf, h2acc[nt], 0, 0, 0);
    }
  __builtin_amdgcn_s_setprio(0);
  __syncthreads();  // B6: all u2T reads done

  // ---- store h2 [node][hid]: hid<128 cols -> R0, else R1 ----
#pragma unroll
  for (int nt = 0; nt < 16; ++nt) {
    float bias = b2g[nt * 16 + l15];
#pragma unroll
    for (int r = 0; r < 4; ++r) {
      int row = m0 + l4 * 4 + r;
      int coll = (nt & 7) * 16 + l15;
      unsigned short* Rd = (nt < 8) ? R0 : R1;
      Rd[row * 128 + SWZ(coll, row)] = f2b(leaky(h2acc[nt][r] + bias));
    }
  }
  __syncthreads();  // B7: h2 stored

  // ---- op4: u3T = W3T @ h2^T, full K=256 (R0 then R1) ----
  f32x4 u3[4] = {};
  const int mrow = (w >> 1) * 16, ntb = (w & 1) * 4;
  __builtin_amdgcn_s_setprio(1);
#pragma unroll
  for (int kh = 0; kh < 2; ++kh) {
    const unsigned short* Rs = kh ? R1 : R0;
#pragma unroll
    for (int ks = 0; ks < 4; ++ks) {
      bf16x8 a3 = *(const bf16x8*)&W3T[(size_t)(mrow + l15) * 256 + kh * 128 + ks * 32 + l4 * 8];
#pragma unroll
      for (int nti = 0; nti < 4; ++nti) {
        int br = (ntb + nti) * 16 + l15;
        bf16x8 bf = *(const bf16x8*)&Rs[br * 128 + SWZ(ks * 32 + l4 * 8, br)];
        u3[nti] = __builtin_amdgcn_mfma_f32_16x16x32_bf16(a3, bf, u3[nti], 0, 0, 0);
      }
    }
  }
  __builtin_amdgcn_s_setprio(0);
  __syncthreads();  // B8: all h2 reads done

  // ---- store u3T [cls][node] -> R0 rows 0..63 ----
#pragma unroll
  for (int nti = 0; nti < 4; ++nti)
#pragma unroll
    for (int r = 0; r < 4; ++r) {
      int grow = mrow + l4 * 4 + r;
      int col = (ntb + nti) * 16 + l15;
      R0[grow * 128 + SWZ(col, grow)] = f2b(u3[nti][r]);
    }
  __syncthreads();  // B9: u3T stored

  // ---- op5: xa = leaky(adj @ u3 + b3); mean over node via shuffles ----
  {
    f32x4 xacc[4] = {};
    __builtin_amdgcn_s_setprio(1);
#pragma unroll
    for (int ks = 0; ks < 4; ++ks)
#pragma unroll
      for (int nt = 0; nt < 4; ++nt) {
        int br = nt * 16 + l15;
        bf16x8 bf = *(const bf16x8*)&R0[br * 128 + SWZ(ks * 32 + l4 * 8, br)];
        xacc[nt] = __builtin_amdgcn_mfma_f32_16x16x32_bf16(afj[ks], bf, xacc[nt], 0, 0, 0);
      }
    __builtin_amdgcn_s_setprio(0);
    float* pf = reinterpret_cast<float*>(R1);  // R1 dead after op4
#pragma unroll
    for (int nt = 0; nt < 4; ++nt) {
      float bias = b3g[nt * 16 + l15];
      float v = 0.f;
#pragma unroll
      for (int r = 0; r < 4; ++r) v += leaky(xacc[nt][r] + bias);
      v += __shfl_xor(v, 16);
      v += __shfl_xor(v, 32);
      if (l4 == 0) pf[w * 64 + nt * 16 + l15] = v;
    }
  }
  __syncthreads();  // B10: partials written
  if (tid < 64) {
    const float* pf = reinterpret_cast<const float*>(R1);
    float s = 0.f;
#pragma unroll
    for (int gg = 0; gg < 8; ++gg) s += pf[gg * 64 + tid];
    gXa[((size_t)b * 15 + a) * 64 + tid] = s * (1.f / 128.f);
  }
}

// ---------------- k_head: per-batch head ----------------
__global__ __launch_bounds__(256) void k_head(const float* __restrict__ gXa,
                                              const float* __restrict__ W4,
                                              const float* __restrict__ b4,
                                              float* __restrict__ out) {
  __shared__ float xb[15 * 64];
  __shared__ float c2[15 * 16];
  __shared__ float mu[15];
  __shared__ float dinv[15];
  __shared__ float yy[15 * 64];
  __shared__ float zz[15 * 64];
  const int b = blockIdx.x;
  const int tid = threadIdx.x;
  for (int e = tid; e < 960; e += 256) xb[e] = gXa[(size_t)b * 960 + e];
  __syncthreads();
  if (tid < 15) {
    float s = 0.f;
    for (int c = 0; c < 64; ++c) s += xb[tid * 64 + c];
    mu[tid] = s * (1.f / 64.f);
  }
  __syncthreads();
  if (tid < 225) {
    int p = tid / 15, q = tid % 15;
    float s = 0.f;
    for (int c = 0; c < 64; ++c)
      s += (xb[p * 64 + c] - mu[p]) * (xb[q * 64 + c] - mu[q]);
    c2[p * 16 + q] = s;
  }
  __syncthreads();
  if (tid < 15) {
    float d = c2[tid * 16 + tid];
    dinv[tid] = d > 0.f ? (1.f / sqrtf(d)) : 0.f;
  }
  __syncthreads();
  if (tid < 225) {
    int p = tid / 15, q = tid % 15;
    float v = c2[p * 16 + q] * dinv[p] * dinv[q];
    v = fminf(1.f, fmaxf(-1.f, v));
    if (dinv[p] == 0.f || dinv[q] == 0.f) v = 0.f;
    c2[p * 16 + q] = v;
  }
  __syncthreads();
  for (int e = tid; e < 960; e += 256) {
    int p = e >> 6, c = e & 63;
    float s = 0.f;
    for (int q = 0; q < 15; ++q) s += c2[p * 16 + q] * xb[q * 64 + c];
    yy[e] = s;
  }
  __syncthreads();
  for (int e = tid; e < 960; e += 256) {
    int p = e >> 6, c = e & 63;
    float s = b4[c];
    for (int k = 0; k < 64; ++k) s += yy[p * 64 + k] * W4[k * 64 + c];
    zz[e] = leaky(s);
  }
  __syncthreads();
  if (tid < 64) {
    float m = -INFINITY;
    for (int p = 0; p < 15; ++p) m = fmaxf(m, zz[p * 64 + tid]);
    out[(size_t)b * 64 + tid] = m;
  }
}

extern "C" void kernel_launch(void* const* d_in, const int* in_sizes, int n_in,
                              void* d_out, int out_size, void* d_ws, size_t ws_size,
                              hipStream_t stream) {
  const float* x  = (const float*)d_in[0];
  const float* W1 = (const float*)d_in[1];
  const float* b1 = (const float*)d_in[2];
  const float* W2 = (const float*)d_in[3];
  const float* b2 = (const float*)d_in[4];
  const float* W3 = (const float*)d_in[5];
  const float* b3 = (const float*)d_in[6];
  const float* W4 = (const float*)d_in[7];
  const float* b4 = (const float*)d_in[8];
  float* out = (float*)d_out;

  char* ws = (char*)d_ws;
  unsigned short* xT   = (unsigned short*)ws;                 // 32*2048*128*2 = 16 MB
  unsigned short* XW1T = (unsigned short*)(ws + 16777216);    // 2 MB
  unsigned short* W1T  = (unsigned short*)(ws + 18874368);    // 1 MB
  unsigned short* W2T  = (unsigned short*)(ws + 19922944);    // 128 KB
  unsigned short* W3T  = (unsigned short*)(ws + 20054016);    // 32 KB
  float* gXa           = (float*)(ws + 20086784);             // 120 KB

  k_prepw<<<148, 256, 0, stream>>>(W1, W2, W3, W1T, W2T, W3T);
  k_front<<<2112, 512, 0, stream>>>(x, W1T, xT, XW1T);
  k_chain<<<480, 512, 0, stream>>>(xT, XW1T, W2T, W3T, b1, b2, b3, gXa);
  k_head<<<32, 256, 0, stream>>>(gXa, W4, b4, out);
}

// Round 10
// 131.301 us; speedup vs baseline: 1.1208x; 1.0203x over previous
//
#include <hip/hip_runtime.h>

// B=32, F=node=128, T=2048, HID=256, NC=64, A=15 windows
// R9 structure; k_chain loop-ified (small code), setprio removed, 1-pass syrk.

typedef float f32x4 __attribute__((ext_vector_type(4)));
typedef __bf16 bf16x8 __attribute__((ext_vector_type(8)));
typedef unsigned short u16x8 __attribute__((ext_vector_type(8)));

__device__ inline unsigned short f2b(float f) {
  unsigned int u = __float_as_uint(f);
  unsigned int r = u + 0x7fffu + ((u >> 16) & 1u);
  return (unsigned short)(r >> 16);
}
__device__ inline float leaky(float v) { return v >= 0.f ? v : 0.2f * v; }

#define SWZ(k, r) ((k) ^ (((r) & 7) << 3))

// ---------------- k_prepw: W1/W2/W3 -> bf16 transposed ----------------
__global__ __launch_bounds__(256) void k_prepw(const float* __restrict__ W1,
                                               const float* __restrict__ W2,
                                               const float* __restrict__ W3,
                                               unsigned short* __restrict__ W1T,
                                               unsigned short* __restrict__ W2T,
                                               unsigned short* __restrict__ W3T) {
  __shared__ float t[64][65];
  const int bid = blockIdx.x;
  const int tid = threadIdx.x;
  const float* src;
  unsigned short* dst;
  int K, N, k0, n0;
  if (bid < 128) {        // W1 [2048][256] -> W1T [256][2048]
    src = W1; dst = W1T; K = 2048; N = 256;
    k0 = (bid >> 2) * 64; n0 = (bid & 3) * 64;
  } else if (bid < 144) { // W2 [256][256] -> W2T [256][256]
    src = W2; dst = W2T; K = 256; N = 256;
    int i = bid - 128; k0 = (i >> 2) * 64; n0 = (i & 3) * 64;
  } else {                // W3 [256][64] -> W3T [64][256]
    src = W3; dst = W3T; K = 256; N = 64;
    int i = bid - 144; k0 = i * 64; n0 = 0;
  }
#pragma unroll
  for (int it = 0; it < 16; ++it) {
    int e = tid + it * 256, r = e >> 6, c = e & 63;
    t[r][c] = src[(size_t)(k0 + r) * N + n0 + c];
  }
  __syncthreads();
#pragma unroll
  for (int it = 0; it < 16; ++it) {
    int e = tid + it * 256, rr = e >> 6, cc = e & 63;
    dst[(size_t)(n0 + rr) * K + k0 + cc] = f2b(t[cc][rr]);
  }
}

// ---------------- k_front: XW1T GEMM (bid<64) + xT transpose (bid>=64) ----
__global__ __launch_bounds__(512) void k_front(const float* __restrict__ x,
                                               const unsigned short* __restrict__ W1T,
                                               unsigned short* __restrict__ xT,
                                               unsigned short* __restrict__ XW1T) {
  __shared__ __align__(16) char ldsbuf[16896];
  const int bid = blockIdx.x;
  const int tid = threadIdx.x;
  if (bid >= 64) {
    // x [b][128 f][2048 t] fp32 -> xT [b][2048 t][128 f] bf16, 64x64 tiles
    float (*t)[65] = reinterpret_cast<float (*)[65]>(ldsbuf);
    int i = bid - 64;
    int b = i >> 6, rem = i & 63;
    int t0 = (rem >> 1) * 64, f0 = (rem & 1) * 64;
    const float* xb = x + ((size_t)b * 128 + f0) * 2048 + t0;
    int r = tid >> 3, c8 = (tid & 7) * 8;
    f32x4 v0 = *(const f32x4*)&xb[(size_t)r * 2048 + c8];
    f32x4 v1 = *(const f32x4*)&xb[(size_t)r * 2048 + c8 + 4];
    *(f32x4*)&t[r][c8] = v0;
    *(f32x4*)&t[r][c8 + 4] = v1;
    __syncthreads();
    u16x8 s;
#pragma unroll
    for (int q = 0; q < 8; ++q) s[q] = f2b(t[c8 + q][r]);
    *(u16x8*)&xT[((size_t)b * 2048 + t0 + r) * 128 + f0 + c8] = s;
  } else {
    // XW1T[b][hid 256][f0+0:64] = (x_b @ W1)^T ; A=W1T (L2), B=x tile (LDS dbuf)
    unsigned short (*sX)[64 * 64] = reinterpret_cast<unsigned short (*)[64 * 64]>(ldsbuf);
    const int b = bid >> 1, f0 = (bid & 1) * 64;
    const int w = tid >> 6, lane = tid & 63;
    const int l15 = lane & 15, l4 = lane >> 4;
    const float* xb = x + ((size_t)b * 128 + f0) * 2048;
    const int fr = tid >> 3, k8 = (tid & 7) * 8;
    f32x4 xr0, xr1;
    f32x4 acc[2][4] = {};

    auto LOADX = [&](int kb) {
      xr0 = *(const f32x4*)&xb[(size_t)fr * 2048 + kb * 64 + k8];
      xr1 = *(const f32x4*)&xb[(size_t)fr * 2048 + kb * 64 + k8 + 4];
    };
    auto STOREX = [&](int buf) {
      u16x8 s;
#pragma unroll
      for (int q = 0; q < 8; ++q) s[q] = f2b(q < 4 ? xr0[q] : xr1[q - 4]);
      *(u16x8*)&sX[buf][fr * 64 + SWZ(k8, fr)] = s;
    };

    LOADX(0);
    STOREX(0);
    __syncthreads();
    for (int kb = 0; kb < 32; ++kb) {
      if (kb < 31) LOADX(kb + 1);
      const int buf = kb & 1;
#pragma unroll
      for (int ks = 0; ks < 2; ++ks) {
        bf16x8 af[2];
#pragma unroll
        for (int mt = 0; mt < 2; ++mt)
          af[mt] = *(const bf16x8*)&W1T[(size_t)(w * 32 + mt * 16 + l15) * 2048 + kb * 64 + ks * 32 + l4 * 8];
#pragma unroll
        for (int nt = 0; nt < 4; ++nt) {
          int br = nt * 16 + l15;
          bf16x8 bf = *(const bf16x8*)&sX[buf][br * 64 + SWZ(ks * 32 + l4 * 8, br)];
#pragma unroll
          for (int mt = 0; mt < 2; ++mt)
            acc[mt][nt] = __builtin_amdgcn_mfma_f32_16x16x32_bf16(af[mt], bf, acc[mt][nt], 0, 0, 0);
        }
      }
      if (kb < 31) {
        STOREX(buf ^ 1);
        __syncthreads();
      }
    }
#pragma unroll
    for (int mt = 0; mt < 2; ++mt)
#pragma unroll
      for (int nt = 0; nt < 4; ++nt)
#pragma unroll
        for (int r = 0; r < 4; ++r) {
          int p = w * 32 + mt * 16 + l4 * 4 + r;
          XW1T[((size_t)b * 256 + p) * 128 + f0 + nt * 16 + l15] = f2b(acc[mt][nt][r]);
        }
  }
}

// ---------------- k_chain: compact-code per-(b,a) fused MFMA chain ----------------
__global__ __launch_bounds__(512) void k_chain(
    const unsigned short* __restrict__ xT, const unsigned short* __restrict__ XW1T,
    const unsigned short* __restrict__ W2T, const unsigned short* __restrict__ W3T,
    const float* __restrict__ b1g, const float* __restrict__ b2g,
    const float* __restrict__ b3g, float* __restrict__ gXa) {
  __shared__ __align__(16) unsigned short R0[128 * 128];  // adj -> h1b -> u2Ta/h2a -> u3T
  __shared__ __align__(16) unsigned short R1[128 * 128];  // win -> h1a -> u2Tb/h2b -> partials
  __shared__ float fS[256];  // [0:128) colsum, [128:256) diag

  const int tid = threadIdx.x;
  const int w = tid >> 6, lane = tid & 63;
  const int l15 = lane & 15, l4 = lane >> 4;
  const int ridx = (blockIdx.x & 7) * 60 + (blockIdx.x >> 3);
  const int b = ridx / 15, a = ridx % 15;
  const int m0 = w * 16;
  const unsigned short* XWb = XW1T + (size_t)b * 256 * 128;
  const float inv128 = 1.f / 128.f;

  // ---- P0: win[node j][f] <- xT into R1 ----
  const unsigned short* src = xT + ((size_t)b * 2048 + (size_t)a * 128) * 128;
#pragma unroll 1
  for (int it = 0; it < 4; ++it) {
    int tt = tid + it * 512;
    int j = tt >> 4, f8 = (tt & 15) * 8;
    *(u16x8*)&R1[j * 128 + SWZ(f8, j)] = *(const u16x8*)&src[j * 128 + f8];
  }
  __syncthreads();  // B0

  // ---- syrk prologue: A-frags, row sums (ones-MFMA), own diag (self-MFMA) ----
  bf16x8 afw[4];
#pragma unroll
  for (int ks = 0; ks < 4; ++ks) {
    int ar = m0 + l15;
    afw[ks] = *(const bf16x8*)&R1[ar * 128 + SWZ(ks * 32 + l4 * 8, ar)];
  }
  bf16x8 ones;
#pragma unroll
  for (int q = 0; q < 8; ++q) ones[q] = (__bf16)1.0f;
  f32x4 sacc = {}, dacc = {};
#pragma unroll
  for (int ks = 0; ks < 4; ++ks) {
    sacc = __builtin_amdgcn_mfma_f32_16x16x32_bf16(afw[ks], ones, sacc, 0, 0, 0);
    dacc = __builtin_amdgcn_mfma_f32_16x16x32_bf16(afw[ks], afw[ks], dacc, 0, 0, 0);
  }
#pragma unroll
  for (int r = 0; r < 4; ++r) {
    if (l15 == 0) fS[m0 + l4 * 4 + r] = sacc[r];
    if (l15 == l4 * 4 + r)  // lane holding C[row][row] of this wave's diag tile
      fS[128 + m0 + l4 * 4 + r] = dacc[r] - sacc[r] * sacc[r] * inv128;
  }
  __syncthreads();  // B1: sums + diag visible

  // ---- syrk main: c -> center -> scale -> clip -> adj bf16 in R0 (one pass) ----
  float div[4];
#pragma unroll
  for (int r = 0; r < 4; ++r) {
    float d = fS[128 + m0 + l4 * 4 + r];
    div[r] = d > 0.f ? __frsqrt_rn(d) : 0.f;
  }
#pragma unroll 1
  for (int nt = 0; nt < 8; ++nt) {
    int col = nt * 16 + l15;
    f32x4 c = {};
#pragma unroll
    for (int ks = 0; ks < 4; ++ks) {
      bf16x8 bf = *(const bf16x8*)&R1[col * 128 + SWZ(ks * 32 + l4 * 8, col)];
      c = __builtin_amdgcn_mfma_f32_16x16x32_bf16(afw[ks], bf, c, 0, 0, 0);
    }
    float fc = fS[col];
    float dc = fS[128 + col];
    float djv = dc > 0.f ? __frsqrt_rn(dc) : 0.f;
#pragma unroll
    for (int r = 0; r < 4; ++r) {
      float v = (c[r] - sacc[r] * fc * inv128) * div[r] * djv;
      v = fminf(1.f, fmaxf(-1.f, v));
      v = 0.5f * v + 0.5f;
      if (div[r] == 0.f || djv == 0.f) v = 0.f;  // nan_to_num
      int row = m0 + l4 * 4 + r;
      R0[row * 128 + SWZ(col, row)] = f2b(v);
    }
  }
  // adj rows m0..m0+15: same-wave write->read (LDS in-order per wave)
  bf16x8 afj[4];
#pragma unroll
  for (int ks = 0; ks < 4; ++ks)
    afj[ks] = *(const bf16x8*)&R0[(m0 + l15) * 128 + SWZ(ks * 32 + l4 * 8, m0 + l15)];
  __syncthreads();  // B2: all waves' R1 (win) reads done before op1 writes R1

  // ---- op1: h1 = leaky(adj @ XW1b + b1); hid0:128 -> R1, hid128:256 -> R0 ----
#pragma unroll 1
  for (int half = 0; half < 2; ++half) {
    unsigned short* Rd = half ? R0 : R1;
#pragma unroll 1
    for (int nt = 0; nt < 8; ++nt) {
      f32x4 acc = {};
      const unsigned short* Bp = &XWb[(size_t)(half * 128 + nt * 16 + l15) * 128 + l4 * 8];
#pragma unroll
      for (int ks = 0; ks < 4; ++ks) {
        bf16x8 bf = *(const bf16x8*)&Bp[ks * 32];
        acc = __builtin_amdgcn_mfma_f32_16x16x32_bf16(afj[ks], bf, acc, 0, 0, 0);
      }
      float bias = b1g[half * 128 + nt * 16 + l15];
#pragma unroll
      for (int r = 0; r < 4; ++r) {
        int row = m0 + l4 * 4 + r;
        Rd[row * 128 + SWZ(nt * 16 + l15, row)] = f2b(leaky(acc[r] + bias));
      }
    }
  }
  __syncthreads();  // B3: h1 complete

  // ---- op2: u2T = W2T @ h1^T, full K=256 (k<128 from R1, k>=128 from R0) ----
  f32x4 u2[2][8] = {};
  {
#pragma unroll
    for (int ks = 0; ks < 8; ++ks) {
      bf16x8 a0 = *(const bf16x8*)&W2T[(size_t)(w * 32 + l15) * 256 + ks * 32 + l4 * 8];
      bf16x8 a1 = *(const bf16x8*)&W2T[(size_t)(w * 32 + 16 + l15) * 256 + ks * 32 + l4 * 8];
      const unsigned short* Rs = (ks < 4) ? R1 : R0;
      int kk = (ks & 3) * 32 + l4 * 8;
#pragma unroll
      for (int nt = 0; nt < 8; ++nt) {
        int br = nt * 16 + l15;
        bf16x8 bf = *(const bf16x8*)&Rs[br * 128 + SWZ(kk, br)];
        u2[0][nt] = __builtin_amdgcn_mfma_f32_16x16x32_bf16(a0, bf, u2[0][nt], 0, 0, 0);
        u2[1][nt] = __builtin_amdgcn_mfma_f32_16x16x32_bf16(a1, bf, u2[1][nt], 0, 0, 0);
      }
    }
  }
  __syncthreads();  // B4: all h1 reads done

#pragma unroll
  for (int mt = 0; mt < 2; ++mt)
#pragma unroll
    for (int nt = 0; nt < 8; ++nt)
#pragma unroll
      for (int r = 0; r < 4; ++r) {
        int grow = w * 32 + mt * 16 + l4 * 4 + r;
        int col = nt * 16 + l15;
        unsigned short* Rd = (grow < 128) ? R0 : R1;
        int lr = grow & 127;
        Rd[lr * 128 + SWZ(col, lr)] = f2b(u2[mt][nt][r]);
      }
  __syncthreads();  // B5: u2T stored

  // ---- op3: h2 = leaky(adj @ u2 + b2), full hid 256 ----
  f32x4 h2acc[16];
#pragma unroll
  for (int nt = 0; nt < 16; ++nt) h2acc[nt] = f32x4{0.f, 0.f, 0.f, 0.f};
#pragma unroll
  for (int ks = 0; ks < 4; ++ks)
#pragma unroll
    for (int nt = 0; nt < 16; ++nt) {
      int brl = (nt & 7) * 16 + l15;
      const unsigned short* Rs = (nt < 8) ? R0 : R1;
      bf16x8 bf = *(const bf16x8*)&Rs[brl * 128 + SWZ(ks * 32 + l4 * 8, brl)];
      h2acc[nt] = __builtin_amdgcn_mfma_f32_16x16x32_bf16(afj[ks], bf, h2acc[nt], 0, 0, 0);
    }
  __syncthreads();  // B6: all u2T reads done

#pragma unroll
  for (int nt = 0; nt < 16; ++nt) {
    float bias = b2g[nt * 16 + l15];
#pragma unroll
    for (int r = 0; r < 4; ++r) {
      int row = m0 + l4 * 4 + r;
      int coll = (nt & 7) * 16 + l15;
      unsigned short* Rd = (nt < 8) ? R0 : R1;
      Rd[row * 128 + SWZ(coll, row)] = f2b(leaky(h2acc[nt][r] + bias));
    }
  }
  __syncthreads();  // B7: h2 stored

  // ---- op4: u3T = W3T @ h2^T, full K=256 (R0 then R1) ----
  f32x4 u3[4] = {};
  const int mrow = (w >> 1) * 16, ntb = (w & 1) * 4;
#pragma unroll
  for (int kh = 0; kh < 2; ++kh) {
    const unsigned short* Rs = kh ? R1 : R0;
#pragma unroll
    for (int ks = 0; ks < 4; ++ks) {
      bf16x8 a3 = *(const bf16x8*)&W3T[(size_t)(mrow + l15) * 256 + kh * 128 + ks * 32 + l4 * 8];
#pragma unroll
      for (int nti = 0; nti < 4; ++nti) {
        int br = (ntb + nti) * 16 + l15;
        bf16x8 bf = *(const bf16x8*)&Rs[br * 128 + SWZ(ks * 32 + l4 * 8, br)];
        u3[nti] = __builtin_amdgcn_mfma_f32_16x16x32_bf16(a3, bf, u3[nti], 0, 0, 0);
      }
    }
  }
  __syncthreads();  // B8: all h2 reads done

#pragma unroll
  for (int nti = 0; nti < 4; ++nti)
#pragma unroll
    for (int r = 0; r < 4; ++r) {
      int grow = mrow + l4 * 4 + r;
      int col = (ntb + nti) * 16 + l15;
      R0[grow * 128 + SWZ(col, grow)] = f2b(u3[nti][r]);
    }
  __syncthreads();  // B9: u3T stored

  // ---- op5: xa = leaky(adj @ u3 + b3); mean over node via shuffles ----
  {
    float* pf = reinterpret_cast<float*>(R1);  // R1 dead after op4
#pragma unroll 1
    for (int nt = 0; nt < 4; ++nt) {
      f32x4 acc = {};
      int br = nt * 16 + l15;
#pragma unroll
      for (int ks = 0; ks < 4; ++ks) {
        bf16x8 bf = *(const bf16x8*)&R0[br * 128 + SWZ(ks * 32 + l4 * 8, br)];
        acc = __builtin_amdgcn_mfma_f32_16x16x32_bf16(afj[ks], bf, acc, 0, 0, 0);
      }
      float bias = b3g[br];
      float v = 0.f;
#pragma unroll
      for (int r = 0; r < 4; ++r) v += leaky(acc[r] + bias);
      v += __shfl_xor(v, 16);
      v += __shfl_xor(v, 32);
      if (l4 == 0) pf[w * 64 + br] = v;
    }
  }
  __syncthreads();  // B10: partials written
  if (tid < 64) {
    const float* pf = reinterpret_cast<const float*>(R1);
    float s = 0.f;
#pragma unroll
    for (int gg = 0; gg < 8; ++gg) s += pf[gg * 64 + tid];
    gXa[((size_t)b * 15 + a) * 64 + tid] = s * (1.f / 128.f);
  }
}

// ---------------- k_head: per-batch head ----------------
__global__ __launch_bounds__(256) void k_head(const float* __restrict__ gXa,
                                              const float* __restrict__ W4,
                                              const float* __restrict__ b4,
                                              float* __restrict__ out) {
  __shared__ float xb[15 * 64];
  __shared__ float c2[15 * 16];
  __shared__ float mu[15];
  __shared__ float dinv[15];
  __shared__ float yy[15 * 64];
  __shared__ float zz[15 * 64];
  const int b = blockIdx.x;
  const int tid = threadIdx.x;
  for (int e = tid; e < 960; e += 256) xb[e] = gXa[(size_t)b * 960 + e];
  __syncthreads();
  if (tid < 15) {
    float s = 0.f;
    for (int c = 0; c < 64; ++c) s += xb[tid * 64 + c];
    mu[tid] = s * (1.f / 64.f);
  }
  __syncthreads();
  if (tid < 225) {
    int p = tid / 15, q = tid % 15;
    float s = 0.f;
    for (int c = 0; c < 64; ++c)
      s += (xb[p * 64 + c] - mu[p]) * (xb[q * 64 + c] - mu[q]);
    c2[p * 16 + q] = s;
  }
  __syncthreads();
  if (tid < 15) {
    float d = c2[tid * 16 + tid];
    dinv[tid] = d > 0.f ? (1.f / sqrtf(d)) : 0.f;
  }
  __syncthreads();
  if (tid < 225) {
    int p = tid / 15, q = tid % 15;
    float v = c2[p * 16 + q] * dinv[p] * dinv[q];
    v = fminf(1.f, fmaxf(-1.f, v));
    if (dinv[p] == 0.f || dinv[q] == 0.f) v = 0.f;
    c2[p * 16 + q] = v;
  }
  __syncthreads();
  for (int e = tid; e < 960; e += 256) {
    int p = e >> 6, c = e & 63;
    float s = 0.f;
    for (int q = 0; q < 15; ++q) s += c2[p * 16 + q] * xb[q * 64 + c];
    yy[e] = s;
  }
  __syncthreads();
  for (int e = tid; e < 960; e += 256) {
    int p = e >> 6, c = e & 63;
    float s = b4[c];
    for (int k = 0; k < 64; ++k) s += yy[p * 64 + k] * W4[k * 64 + c];
    zz[e] = leaky(s);
  }
  __syncthreads();
  if (tid < 64) {
    float m = -INFINITY;
    for (int p = 0; p < 15; ++p) m = fmaxf(m, zz[p * 64 + tid]);
    out[(size_t)b * 64 + tid] = m;
  }
}

extern "C" void kernel_launch(void* const* d_in, const int* in_sizes, int n_in,
                              void* d_out, int out_size, void* d_ws, size_t ws_size,
                              hipStream_t stream) {
  const float* x  = (const float*)d_in[0];
  const float* W1 = (const float*)d_in[1];
  const float* b1 = (const float*)d_in[2];
  const float* W2 = (const float*)d_in[3];
  const float* b2 = (const float*)d_in[4];
  const float* W3 = (const float*)d_in[5];
  const float* b3 = (const float*)d_in[6];
  const float* W4 = (const float*)d_in[7];
  const float* b4 = (const float*)d_in[8];
  float* out = (float*)d_out;

  char* ws = (char*)d_ws;
  unsigned short* xT   = (unsigned short*)ws;                 // 32*2048*128*2 = 16 MB
  unsigned short* XW1T = (unsigned short*)(ws + 16777216);    // 2 MB
  unsigned short* W1T  = (unsigned short*)(ws + 18874368);    // 1 MB
  unsigned short* W2T  = (unsigned short*)(ws + 19922944);    // 128 KB
  unsigned short* W3T  = (unsigned short*)(ws + 20054016);    // 32 KB
  float* gXa           = (float*)(ws + 20086784);             // 120 KB

  k_prepw<<<148, 256, 0, stream>>>(W1, W2, W3, W1T, W2T, W3T);
  k_front<<<2112, 512, 0, stream>>>(x, W1T, xT, XW1T);
  k_chain<<<480, 512, 0, stream>>>(xT, XW1T, W2T, W3T, b1, b2, b3, gXa);
  k_head<<<32, 256, 0, stream>>>(gXa, W4, b4, out);
}